// Round 4
// baseline (8860.852 us; speedup 1.0000x reference)
//
#include <hip/hip_runtime.h>
#include <math.h>

#define B_TOT 512
#define T_FR  18
#define NSTEP 16

typedef __attribute__((ext_vector_type(8))) short bf16x8;
typedef __attribute__((ext_vector_type(4))) float f32x4;

__device__ __forceinline__ float gelu_f(float x) {
    return 0.5f * x * (1.0f + erff(x * 0.70710678118654752f));
}
__device__ __forceinline__ float sigmoid_f(float x) {
    return 1.0f / (1.0f + expf(-x));
}
__device__ __forceinline__ short f2bf(float x) {
    unsigned int u = __float_as_uint(x);
    return (short)((u + 0x7FFFu + ((u >> 16) & 1u)) >> 16);
}
__device__ __forceinline__ float bflo(unsigned int u) { return __uint_as_float(u << 16); }
__device__ __forceinline__ float bfhi(unsigned int u) { return __uint_as_float(u & 0xffff0000u); }
// 8 bf16 from 8-byte-aligned LDS (132-short row strides are only 8B aligned)
__device__ __forceinline__ bf16x8 ld_bf8(const short* p) {
    const short4 lo = *reinterpret_cast<const short4*>(p);
    const short4 hi = *reinterpret_cast<const short4*>(p + 4);
    bf16x8 r;
    r[0] = lo.x; r[1] = lo.y; r[2] = lo.z; r[3] = lo.w;
    r[4] = hi.x; r[5] = hi.y; r[6] = hi.z; r[7] = hi.w;
    return r;
}

// ---------------------------------------------------------------- init ----
__global__ __launch_bounds__(256) void init_kernel(
    const float* __restrict__ slot_mu,
    const float* __restrict__ mask_w, const float* __restrict__ mask_b,
    const float* __restrict__ e2w,
    const float* __restrict__ wih, const float* __restrict__ whh,
    const float* __restrict__ qw,
    const float* __restrict__ tsw, const float* __restrict__ tsb,
    const float* __restrict__ kw, const float* __restrict__ vw,
    float* __restrict__ slots_g, float* __restrict__ rmw, float* __restrict__ rmb,
    float* __restrict__ kbf, float* __restrict__ vbf,
    short* __restrict__ w2bf, short* __restrict__ wihbf, short* __restrict__ whhbf,
    short* __restrict__ qwbf, short* __restrict__ kwf, short* __restrict__ vwf)
{
    const int tid = threadIdx.x, bid = blockIdx.x;
    const int gid = bid * 256 + tid, gstr = gridDim.x * 256;
    const float rscale = 0.08838834764831845f;  // 1/sqrt(128)

    for (int i = gid; i < B_TOT * 1024; i += gstr) slots_g[i] = slot_mu[i & 1023];
    for (int i = gid; i < 128 * 2048; i += gstr) w2bf[i] = f2bf(e2w[i]);
    for (int i = gid; i < 384 * 128; i += gstr) {
        wihbf[i] = f2bf(wih[i]);
        whhbf[i] = f2bf(whh[i]);
    }
    for (int i = gid; i < 128 * 128; i += gstr) qwbf[i] = f2bf(qw[i] * rscale);

    // fused kk/vv weights: kwf[j][c] = sum_d kw[j][d]*tsw[d][c]; kbf[j] = kw[j]·tsb
    if (bid < 128) {
        const int j = bid;
        if (tid < 128) {
            const int c = tid;
            float s = 0.f;
            for (int d = 0; d < 128; ++d) s += kw[j * 128 + d] * tsw[d * 128 + c];
            kwf[j * 128 + c] = f2bf(s);
        } else if (tid == 128) {
            float s = 0.f;
            for (int d = 0; d < 128; ++d) s += kw[j * 128 + d] * tsb[d];
            kbf[j] = s;
        }
    } else if (bid < 256) {
        const int j = bid - 128;
        if (tid < 128) {
            const int c = tid;
            float s = 0.f;
            for (int d = 0; d < 128; ++d) s += vw[j * 128 + d] * tsw[d * 128 + c];
            vwf[j * 128 + c] = f2bf(s);
        } else if (tid == 128) {
            float s = 0.f;
            for (int d = 0; d < 128; ++d) s += vw[j * 128 + d] * tsb[d];
            vbf[j] = s;
        }
    }
    // reduced mask weights (mean over 128 channel copies)
    if (bid == 256) {
        for (int i = tid; i < 2048; i += 256) {
            const int j = i >> 7, d = i & 127;
            float s = 0.f;
            for (int c = 0; c < 128; ++c) s += mask_w[(c * 16 + j) * 128 + d];
            rmw[i] = s * (1.0f / 128.0f);
        }
        for (int i = tid; i < 16; i += 256) {
            float s = 0.f;
            for (int c = 0; c < 128; ++c) s += mask_b[c * 16 + i];
            rmb[i] = s * (1.0f / 128.0f);
        }
    }
}

// ------------------------------------------------ fused per-step kernel ----
// 64 blocks x 512 threads; each block owns 8 batch elements.
// LDS pool offsets (bytes):
#define O_PAIR 0        // A: f32[8][2][256] = 16384
#define O_E1W  16384    // A: f32[2304] = 9216 ; e1b at 25600 (512)
#define O_E1B  25600
#define O_F1S  26112    // A: bf16[16ci][8b][320] = 81920 (end 108032)
#define O_F2T  0        // B: bf16[128][132] = 33792
#define O_KKL  33792    // B/C: bf16[128][132] (end 67584)
#define O_VVL  67584    // B/C: bf16[128][132] (end 101376)
#define O_QQB  0        // C: bf16[64][132] = 16896
#define O_UPDB 16896    // C: bf16[64][132] (end 33792)
#define O_SLB  101376   // C/D: bf16[64][132] (end 118272)
#define O_ATT  118272   // C: f32[1024] = 4096 (end 122368)
#define O_MASK 0        // D: f32[8][8][256] = 65536
#define O_IMG  65536    // D: f32[2048] = 8192
#define O_WARP 73728    // D: f32[2048] = 8192
#define O_DIFF 81920    // D: f32[2048] = 8192
#define O_M1   90112    // D: f32[8][8][32] = 8192 (end 98304)
#define O_MOT  98304    // D: f32[128] = 512
#define O_ML   118272   // D: f32[8][128] = 4096 (attn dead)
#define O_R1   0        // D: f32[8][8][256] (masks dead after warp)
#define POOLSZ 122368

__global__ __launch_bounds__(512, 2) void step_kernel(
    const float* __restrict__ frames,
    const short* __restrict__ w2bf, const float* __restrict__ e2b,
    const float* __restrict__ e1w_g, const float* __restrict__ e1b_g,
    const short* __restrict__ kwf, const short* __restrict__ vwf,
    const float* __restrict__ kbf, const float* __restrict__ vbf,
    const short* __restrict__ qwbf,
    const short* __restrict__ wihbf, const short* __restrict__ whhbf,
    const float* __restrict__ bih, const float* __restrict__ bhh,
    const float* __restrict__ m1w, const float* __restrict__ m1b,
    const float* __restrict__ m2w, const float* __restrict__ m2b,
    const float* __restrict__ upw, const float* __restrict__ upb,
    const float* __restrict__ r1w, const float* __restrict__ r1b,
    const float* __restrict__ r2w, const float* __restrict__ r2b,
    const float* __restrict__ rmw, const float* __restrict__ rmb,
    float* __restrict__ slots_g, float* __restrict__ out, int step)
{
    __shared__ __align__(16) char POOL[POOLSZ];
    const int tid = threadIdx.x;
    const int lane = tid & 63, w = tid >> 6;        // 8 waves
    const int g = lane >> 4, cn = lane & 15;
    const int bg = blockIdx.x * 8;                   // first batch index

    float* pairL = (float*)(POOL + O_PAIR);
    float* e1wL  = (float*)(POOL + O_E1W);
    float* e1bL  = (float*)(POOL + O_E1B);
    short* f1s   = (short*)(POOL + O_F1S);
    short* f2T   = (short*)(POOL + O_F2T);
    short* kkL   = (short*)(POOL + O_KKL);
    short* vvL   = (short*)(POOL + O_VVL);
    short* qqB   = (short*)(POOL + O_QQB);
    short* updB  = (short*)(POOL + O_UPDB);
    short* slB   = (short*)(POOL + O_SLB);
    float* attW  = (float*)(POOL + O_ATT);

    // ---------------- phase A: pair + e1w load ----------------
    for (int i = 0; i < 8; ++i) {
        const int idx = tid + 512 * i;               // [0,4096)
        const int b_l = idx >> 9, ch = (idx >> 8) & 1, p = idx & 255;
        pairL[(b_l * 2 + ch) * 256 + p] =
            frames[((size_t)(bg + b_l) * T_FR + step + 1 - ch) * 256 + p];
    }
    for (int i = tid; i < 2304; i += 512) e1wL[i] = e1w_g[i];
    if (tid < 128) e1bL[tid] = e1b_g[tid];
    __syncthreads();

    // ---------------- conv1 (VALU) + enc2 (MFMA), 8 ci-chunks ----------------
    const int px = tid & 255, bp = tid >> 8;         // this thread's pixel; 2 b-groups
    const int py = px >> 4, pxx = px & 15;
    const int bcol = (4 * (cn >> 2) + (g & 1) * 2) * 20 + 4 * (cn & 3);
    f32x4 eacc[8];
#pragma unroll
    for (int i = 0; i < 8; ++i) eacc[i] = (f32x4){0.f, 0.f, 0.f, 0.f};

    for (int chunk = 0; chunk < 8; ++chunk) {
        // conv1: 4 b's per thread, 16 ci
        for (int bq = 0; bq < 4; ++bq) {
            const int b_l = bq * 2 + bp;
            float nb0[9], nb1[9];
#pragma unroll
            for (int ky = 0; ky < 3; ++ky)
#pragma unroll
            for (int kx = 0; kx < 3; ++kx) {
                const int yy = py + ky - 1, xx = pxx + kx - 1;
                const bool ok = (yy >= 0 && yy < 16 && xx >= 0 && xx < 16);
                nb0[ky * 3 + kx] = ok ? pairL[(b_l * 2) * 256 + yy * 16 + xx] : 0.f;
                nb1[ky * 3 + kx] = ok ? pairL[(b_l * 2 + 1) * 256 + yy * 16 + xx] : 0.f;
            }
#pragma unroll 4
            for (int j = 0; j < 16; ++j) {
                const int ci = chunk * 16 + j;
                const float* wr = &e1wL[ci * 18];
                float a = e1bL[ci];
#pragma unroll
                for (int q = 0; q < 9; ++q) a += nb0[q] * wr[q] + nb1[q] * wr[q + 9];
                f1s[(j * 8 + b_l) * 320 + py * 20 + pxx] = f2bf(gelu_f(a));
            }
        }
        __syncthreads();
        // enc2 MFMA: wave w owns co rows [16w,16w+16)
        for (int kt = 0; kt < 8; ++kt) {
            const bf16x8 af = *(const bf16x8*)
                &w2bf[(size_t)(w * 16 + cn) * 2048 + chunk * 256 + kt * 32 + g * 8];
            const int rbase = (2 * kt + (g >> 1)) * 2560 + bcol;
#pragma unroll
            for (int b_l = 0; b_l < 8; ++b_l) {
                const short4 lo = *(const short4*)&f1s[rbase + b_l * 320];
                const short4 hi = *(const short4*)&f1s[rbase + b_l * 320 + 20];
                bf16x8 bfr;
                bfr[0] = lo.x; bfr[1] = lo.y; bfr[2] = lo.z; bfr[3] = lo.w;
                bfr[4] = hi.x; bfr[5] = hi.y; bfr[6] = hi.z; bfr[7] = hi.w;
                eacc[b_l] = __builtin_amdgcn_mfma_f32_16x16x32_bf16(af, bfr, eacc[b_l], 0, 0, 0);
            }
        }
        __syncthreads();
    }
    // epilogue: f2T[(b,n)][co] bf16
    {
        const int co0 = w * 16 + 4 * g;
#pragma unroll
        for (int b_l = 0; b_l < 8; ++b_l) {
            short4 sv;
            sv.x = f2bf(gelu_f(eacc[b_l][0] + e2b[co0]));
            sv.y = f2bf(gelu_f(eacc[b_l][1] + e2b[co0 + 1]));
            sv.z = f2bf(gelu_f(eacc[b_l][2] + e2b[co0 + 2]));
            sv.w = f2bf(gelu_f(eacc[b_l][3] + e2b[co0 + 3]));
            *(short4*)&f2T[(b_l * 16 + cn) * 132 + co0] = sv;
        }
    }
    __syncthreads();

    // ---------------- kk/vv MFMA (fused weights) + slot load ----------------
    {
        // wave w = batch b_l = w; A = f2T rows [16w,16w+16)
        for (int mat = 0; mat < 2; ++mat) {
            const short* wf = mat ? vwf : kwf;
            const float* bf = mat ? vbf : kbf;
            short* dst = mat ? vvL : kkL;
            f32x4 acc[8];
#pragma unroll
            for (int nt = 0; nt < 8; ++nt) acc[nt] = (f32x4){0.f, 0.f, 0.f, 0.f};
            for (int kt = 0; kt < 4; ++kt) {
                const bf16x8 af = ld_bf8(&f2T[(w * 16 + cn) * 132 + kt * 32 + g * 8]);
#pragma unroll
                for (int nt = 0; nt < 8; ++nt) {
                    const bf16x8 bfr = *(const bf16x8*)
                        &wf[(size_t)(nt * 16 + cn) * 128 + kt * 32 + g * 8];
                    acc[nt] = __builtin_amdgcn_mfma_f32_16x16x32_bf16(af, bfr, acc[nt], 0, 0, 0);
                }
            }
#pragma unroll
            for (int nt = 0; nt < 8; ++nt) {
                const float bb = bf[nt * 16 + cn];
#pragma unroll
                for (int r = 0; r < 4; ++r)
                    dst[(w * 16 + 4 * g + r) * 132 + nt * 16 + cn] = f2bf(acc[nt][r] + bb);
            }
        }
    }

    // slot state: wave w -> M-tile mw=w&3 (rows), col-half h=w>>2
    const int mw = w & 3, hh = w >> 2;
    float hreg[4][4];   // [nt][r]
    {
#pragma unroll
        for (int nt = 0; nt < 4; ++nt)
#pragma unroll
        for (int r = 0; r < 4; ++r) {
            const int row = mw * 16 + 4 * g + r;          // b_l*8 + k
            const int col = hh * 64 + nt * 16 + cn;
            const float v = slots_g[(size_t)(bg + (row >> 3)) * 1024 + (row & 7) * 128 + col];
            hreg[nt][r] = v;
            slB[row * 132 + col] = f2bf(v);
        }
    }
    __syncthreads();

    // ---------------- slot attention: 3 iterations ----------------
    for (int iter = 0; iter < 3; ++iter) {
        // qq MFMA: A = slB tile mw, B = qwbf cols hh*64..
        {
            f32x4 qa[4];
#pragma unroll
            for (int nt = 0; nt < 4; ++nt) qa[nt] = (f32x4){0.f, 0.f, 0.f, 0.f};
            for (int kt = 0; kt < 4; ++kt) {
                const bf16x8 af = ld_bf8(&slB[(mw * 16 + cn) * 132 + kt * 32 + g * 8]);
#pragma unroll
                for (int nt = 0; nt < 4; ++nt) {
                    const bf16x8 bfr = *(const bf16x8*)
                        &qwbf[(size_t)(hh * 64 + nt * 16 + cn) * 128 + kt * 32 + g * 8];
                    qa[nt] = __builtin_amdgcn_mfma_f32_16x16x32_bf16(af, bfr, qa[nt], 0, 0, 0);
                }
            }
#pragma unroll
            for (int nt = 0; nt < 4; ++nt)
#pragma unroll
            for (int r = 0; r < 4; ++r)
                qqB[(mw * 16 + 4 * g + r) * 132 + hh * 64 + nt * 16 + cn] = f2bf(qa[nt][r]);
        }
        __syncthreads();
        // logits: attW[b][k][n] = qq[b,k]·kk[b,n]   (1024 items, 2/thread)
#pragma unroll
        for (int rep = 0; rep < 2; ++rep) {
            const int i = tid + rep * 512;
            const int n = i & 15, k = (i >> 4) & 7, b = i >> 7;
            const short* qr = &qqB[(b * 8 + k) * 132];
            const short* kr = &kkL[(b * 16 + n) * 132];
            float a = 0.f;
            for (int d = 0; d < 128; d += 4) {
                const uint2 qa_ = *(const uint2*)&qr[d];
                const uint2 ka_ = *(const uint2*)&kr[d];
                a += bflo(qa_.x) * bflo(ka_.x) + bfhi(qa_.x) * bfhi(ka_.x)
                   + bflo(qa_.y) * bflo(ka_.y) + bfhi(qa_.y) * bfhi(ka_.y);
            }
            attW[(b * 8 + k) * 16 + n] = a;
        }
        __syncthreads();
        // softmax over k (per b,n)
        if (tid < 128) {
            const int b = tid >> 4, n = tid & 15;
            float m = -1e30f;
#pragma unroll
            for (int k = 0; k < 8; ++k) m = fmaxf(m, attW[(b * 8 + k) * 16 + n]);
            float e[8], ssum = 0.f;
#pragma unroll
            for (int k = 0; k < 8; ++k) {
                e[k] = expf(attW[(b * 8 + k) * 16 + n] - m);
                ssum += e[k];
            }
            const float inv = 1.f / ssum;
#pragma unroll
            for (int k = 0; k < 8; ++k) attW[(b * 8 + k) * 16 + n] = e[k] * inv;
        }
        __syncthreads();
        // upd[row][d] = sum_n attn*vv -> bf16
        {
            const int row = tid >> 3, dq = (tid & 7) * 16;
            const int b = row >> 3, k = row & 7;
            float acc[16];
#pragma unroll
            for (int q = 0; q < 16; ++q) acc[q] = 0.f;
            for (int n = 0; n < 16; ++n) {
                const float a = attW[(b * 8 + k) * 16 + n];
                const short* vr = &vvL[(b * 16 + n) * 132 + dq];
#pragma unroll
                for (int q = 0; q < 4; ++q) {
                    const uint2 v2 = *(const uint2*)&vr[q * 4];
                    acc[q * 4 + 0] += a * bflo(v2.x);
                    acc[q * 4 + 1] += a * bfhi(v2.x);
                    acc[q * 4 + 2] += a * bflo(v2.y);
                    acc[q * 4 + 3] += a * bfhi(v2.y);
                }
            }
#pragma unroll
            for (int q = 0; q < 4; ++q) {
                short4 sv;
                sv.x = f2bf(acc[q * 4 + 0]); sv.y = f2bf(acc[q * 4 + 1]);
                sv.z = f2bf(acc[q * 4 + 2]); sv.w = f2bf(acc[q * 4 + 3]);
                *(short4*)&updB[row * 132 + dq + q * 4] = sv;
            }
        }
        __syncthreads();
        // GRU MFMA: wave (mw,hh); A-frags then barrier, B from global
        {
            bf16x8 aU[4], aS[4];
#pragma unroll
            for (int kt = 0; kt < 4; ++kt) {
                aU[kt] = ld_bf8(&updB[(mw * 16 + cn) * 132 + kt * 32 + g * 8]);
                aS[kt] = ld_bf8(&slB[(mw * 16 + cn) * 132 + kt * 32 + g * 8]);
            }
            __syncthreads();   // all A-frags in regs before slB is overwritten
#pragma unroll
            for (int nt = 0; nt < 4; ++nt) {
                const int colg = hh * 64 + nt * 16 + cn;
                f32x4 aR = {0.f, 0.f, 0.f, 0.f}, aZ = {0.f, 0.f, 0.f, 0.f};
                f32x4 aNI = {0.f, 0.f, 0.f, 0.f}, aNH = {0.f, 0.f, 0.f, 0.f};
#pragma unroll
                for (int kt = 0; kt < 4; ++kt) {
                    const int ko = kt * 32 + g * 8;
                    const bf16x8 bIr = *(const bf16x8*)&wihbf[(size_t)colg * 128 + ko];
                    const bf16x8 bHr = *(const bf16x8*)&whhbf[(size_t)colg * 128 + ko];
                    const bf16x8 bIz = *(const bf16x8*)&wihbf[(size_t)(128 + colg) * 128 + ko];
                    const bf16x8 bHz = *(const bf16x8*)&whhbf[(size_t)(128 + colg) * 128 + ko];
                    const bf16x8 bIn = *(const bf16x8*)&wihbf[(size_t)(256 + colg) * 128 + ko];
                    const bf16x8 bHn = *(const bf16x8*)&whhbf[(size_t)(256 + colg) * 128 + ko];
                    aR = __builtin_amdgcn_mfma_f32_16x16x32_bf16(aU[kt], bIr, aR, 0, 0, 0);
                    aR = __builtin_amdgcn_mfma_f32_16x16x32_bf16(aS[kt], bHr, aR, 0, 0, 0);
                    aZ = __builtin_amdgcn_mfma_f32_16x16x32_bf16(aU[kt], bIz, aZ, 0, 0, 0);
                    aZ = __builtin_amdgcn_mfma_f32_16x16x32_bf16(aS[kt], bHz, aZ, 0, 0, 0);
                    aNI = __builtin_amdgcn_mfma_f32_16x16x32_bf16(aU[kt], bIn, aNI, 0, 0, 0);
                    aNH = __builtin_amdgcn_mfma_f32_16x16x32_bf16(aS[kt], bHn, aNH, 0, 0, 0);
                }
                const float br = bih[colg] + bhh[colg];
                const float bz = bih[128 + colg] + bhh[128 + colg];
                const float bin = bih[256 + colg], bhn = bhh[256 + colg];
#pragma unroll
                for (int r = 0; r < 4; ++r) {
                    const float rr = sigmoid_f(aR[r] + br);
                    const float zz = sigmoid_f(aZ[r] + bz);
                    const float nn = tanhf(aNI[r] + bin + rr * (aNH[r] + bhn));
                    const float hv = (1.f - zz) * nn + zz * hreg[nt][r];
                    hreg[nt][r] = hv;
                    slB[(mw * 16 + 4 * g + r) * 132 + colg] = f2bf(hv);
                }
            }
        }
        __syncthreads();
    }

    // persist slots
#pragma unroll
    for (int nt = 0; nt < 4; ++nt)
#pragma unroll
    for (int r = 0; r < 4; ++r) {
        const int row = mw * 16 + 4 * g + r;
        const int col = hh * 64 + nt * 16 + cn;
        slots_g[(size_t)(bg + (row >> 3)) * 1024 + (row & 7) * 128 + col] = hreg[nt][r];
    }

    // ---------------- decode ----------------
    float* M1   = (float*)(POOL + O_M1);
    float* MOT  = (float*)(POOL + O_MOT);
    float* ML   = (float*)(POOL + O_ML);
    float* MASK = (float*)(POOL + O_MASK);
    float* IMG  = (float*)(POOL + O_IMG);
    float* WARP = (float*)(POOL + O_WARP);
    float* DIFF = (float*)(POOL + O_DIFF);
    float* R1   = (float*)(POOL + O_R1);

    // img load (pair region is long dead)
    for (int i = 0; i < 4; ++i) {
        const int idx = tid + 512 * i;
        const int b_l = idx >> 8, p = idx & 255;
        IMG[b_l * 256 + p] = frames[((size_t)(bg + b_l) * T_FR + step + 1) * 256 + p];
    }
    // m1: thread -> (b, k, 4 c's)
    {
        const int b = tid >> 6, k = (tid >> 3) & 7, c0 = (tid & 7) * 4;
        const short* sr = &slB[(b * 8 + k) * 132];
        float a0 = m1b[c0], a1 = m1b[c0 + 1], a2 = m1b[c0 + 2], a3 = m1b[c0 + 3];
        for (int d = 0; d < 128; d += 4) {
            const uint2 s2 = *(const uint2*)&sr[d];
            const float s0 = bflo(s2.x), s1 = bfhi(s2.x), s2f = bflo(s2.y), s3 = bfhi(s2.y);
            const float4 w0 = *(const float4*)&m1w[(c0 + 0) * 128 + d];
            const float4 w1 = *(const float4*)&m1w[(c0 + 1) * 128 + d];
            const float4 w2 = *(const float4*)&m1w[(c0 + 2) * 128 + d];
            const float4 w3 = *(const float4*)&m1w[(c0 + 3) * 128 + d];
            a0 += w0.x * s0 + w0.y * s1 + w0.z * s2f + w0.w * s3;
            a1 += w1.x * s0 + w1.y * s1 + w1.z * s2f + w1.w * s3;
            a2 += w2.x * s0 + w2.y * s1 + w2.z * s2f + w2.w * s3;
            a3 += w3.x * s0 + w3.y * s1 + w3.z * s2f + w3.w * s3;
        }
        M1[(b * 8 + k) * 32 + c0] = gelu_f(a0);
        M1[(b * 8 + k) * 32 + c0 + 1] = gelu_f(a1);
        M1[(b * 8 + k) * 32 + c0 + 2] = gelu_f(a2);
        M1[(b * 8 + k) * 32 + c0 + 3] = gelu_f(a3);
    }
    // ml: 1024 items
#pragma unroll
    for (int rep = 0; rep < 2; ++rep) {
        const int i = tid + rep * 512;
        const int b = i >> 7, k = (i >> 4) & 7, j = i & 15;
        const short* sr = &slB[(b * 8 + k) * 132];
        float a = rmb[j];
        for (int d = 0; d < 128; d += 4) {
            const uint2 s2 = *(const uint2*)&sr[d];
            const float4 w4 = *(const float4*)&rmw[j * 128 + d];
            a += w4.x * bflo(s2.x) + w4.y * bfhi(s2.x) + w4.z * bflo(s2.y) + w4.w * bfhi(s2.y);
        }
        ML[b * 128 + k * 16 + j] = a;
    }
    __syncthreads();
    // motion MLP stage 2
    if (tid < 128) {
        const int b = tid >> 4, k = (tid >> 1) & 7, e = tid & 1;
        float a = m2b[e];
#pragma unroll
        for (int c = 0; c < 32; ++c) a += M1[(b * 8 + k) * 32 + c] * m2w[e * 32 + c];
        MOT[(b * 8 + k) * 2 + e] = tanhf(a) * 4.0f;
    }
    __syncthreads();
    // mask logits (transposed conv, non-overlapping) + softmax over k
    {
        const int b = tid >> 6, p0 = (tid & 63) * 4;
#pragma unroll
        for (int pi = 0; pi < 4; ++pi) {
            const int p = p0 + pi;
            const int yy = p >> 4, xx = p & 15;
            const int jj = (yy >> 2) * 4 + (xx >> 2);
            const int wq = (yy & 3) * 4 + (xx & 3);
#pragma unroll
            for (int k = 0; k < 8; ++k) {
                float a = upb[k];
#pragma unroll
                for (int i8 = 0; i8 < 8; ++i8)
                    a += ML[b * 128 + i8 * 16 + jj] * upw[(i8 * 8 + k) * 16 + wq];
                MASK[(b * 8 + k) * 256 + p] = a;
            }
        }
    }
    __syncthreads();
    {
        const int b = tid >> 6, p0 = (tid & 63) * 4;
#pragma unroll
        for (int pi = 0; pi < 4; ++pi) {
            const int p = p0 + pi;
            float m = -1e30f;
#pragma unroll
            for (int k = 0; k < 8; ++k) m = fmaxf(m, MASK[(b * 8 + k) * 256 + p]);
            float e[8], ssum = 0.f;
#pragma unroll
            for (int k = 0; k < 8; ++k) {
                e[k] = expf(MASK[(b * 8 + k) * 256 + p] - m);
                ssum += e[k];
            }
            const float inv = 1.f / ssum;
#pragma unroll
            for (int k = 0; k < 8; ++k) MASK[(b * 8 + k) * 256 + p] = e[k] * inv;
        }
    }
    __syncthreads();
    // warp + diff
    {
        const int b = tid >> 6, p0 = (tid & 63) * 4;
#pragma unroll
        for (int pi = 0; pi < 4; ++pi) {
            const int p = p0 + pi;
            const int yy = p >> 4, xx = p & 15;
            const float gxv = -1.0f + (2.0f / 15.0f) * xx;
            const float gyv = -1.0f + (2.0f / 15.0f) * yy;
            float wsum = 0.f;
#pragma unroll
            for (int k = 0; k < 8; ++k) {
                const float fx = MOT[(b * 8 + k) * 2 + 0] * 0.125f;
                const float fy = MOT[(b * 8 + k) * 2 + 1] * 0.125f;
                const float sgx = fminf(fmaxf(gxv + fx, -1.f), 1.f);
                const float sgy = fminf(fmaxf(gyv + fy, -1.f), 1.f);
                const float ix = (sgx + 1.f) * 7.5f;
                const float iy = (sgy + 1.f) * 7.5f;
                const float x0f = floorf(ix), y0f = floorf(iy);
                const float wx = ix - x0f, wy = iy - y0f;
                const int x0 = (int)x0f, y0 = (int)y0f;
                const int x1 = min(x0 + 1, 15), y1 = min(y0 + 1, 15);
                const float v00 = IMG[b * 256 + y0 * 16 + x0], v01 = IMG[b * 256 + y0 * 16 + x1];
                const float v10 = IMG[b * 256 + y1 * 16 + x0], v11 = IMG[b * 256 + y1 * 16 + x1];
                const float val = (1.f - wy) * ((1.f - wx) * v00 + wx * v01) +
                                  wy * ((1.f - wx) * v10 + wx * v11);
                wsum += MASK[(b * 8 + k) * 256 + p] * val;
            }
            WARP[b * 256 + p] = wsum;
            DIFF[b * 256 + p] = wsum - IMG[b * 256 + p];
        }
    }
    __syncthreads();
    // residual conv (64 ch in 8-ch chunks staged in R1)
    {
        const int b = tid >> 6, p0 = (tid & 63) * 4;
        float racc[4] = {0.f, 0.f, 0.f, 0.f};
        for (int c0 = 0; c0 < 64; c0 += 8) {
#pragma unroll
            for (int pi = 0; pi < 4; ++pi) {
                const int p = p0 + pi;
                const int yy = p >> 4, xx = p & 15;
                float nbz[9];
#pragma unroll
                for (int ky = 0; ky < 3; ++ky)
#pragma unroll
                for (int kx = 0; kx < 3; ++kx) {
                    const int y2 = yy + ky - 1, x2 = xx + kx - 1;
                    const bool ok = (y2 >= 0 && y2 < 16 && x2 >= 0 && x2 < 16);
                    nbz[ky * 3 + kx] = ok ? DIFF[b * 256 + y2 * 16 + x2] : 0.f;
                }
#pragma unroll
                for (int cl = 0; cl < 8; ++cl) {
                    const int c = c0 + cl;
                    float a = r1b[c];
#pragma unroll
                    for (int q = 0; q < 9; ++q) a += nbz[q] * r1w[c * 9 + q];
                    R1[(cl * 8 + b) * 256 + p] = gelu_f(a);
                }
            }
            __syncthreads();
#pragma unroll
            for (int pi = 0; pi < 4; ++pi) {
                const int p = p0 + pi;
                const int yy = p >> 4, xx = p & 15;
#pragma unroll
                for (int cl = 0; cl < 8; ++cl) {
                    const float* r2r = &r2w[(c0 + cl) * 9];
#pragma unroll
                    for (int ky = 0; ky < 3; ++ky)
#pragma unroll
                    for (int kx = 0; kx < 3; ++kx) {
                        const int y2 = yy + ky - 1, x2 = xx + kx - 1;
                        if (y2 >= 0 && y2 < 16 && x2 >= 0 && x2 < 16)
                            racc[pi] += R1[(cl * 8 + b) * 256 + y2 * 16 + x2] * r2r[ky * 3 + kx];
                    }
                }
            }
            __syncthreads();
        }
#pragma unroll
        for (int pi = 0; pi < 4; ++pi) {
            const int p = p0 + pi;
            const float resv = tanhf(racc[pi] + r2b[0]) * 0.1f;
            const float pred = fminf(fmaxf(WARP[b * 256 + p] + resv, 0.f), 1.f);
            out[((size_t)(bg + b) * NSTEP + step) * 256 + p] = pred;
        }
    }
}

// -------------------------------------------------------------- launch ----
extern "C" void kernel_launch(void* const* d_in, const int* in_sizes, int n_in,
                              void* d_out, int out_size, void* d_ws, size_t ws_size,
                              hipStream_t stream)
{
    const float* frames = (const float*)d_in[0];
    const float* e1w = (const float*)d_in[1];
    const float* e1b = (const float*)d_in[2];
    const float* e2w = (const float*)d_in[3];
    const float* e2b = (const float*)d_in[4];
    const float* slot_mu = (const float*)d_in[5];
    const float* tsw = (const float*)d_in[6];
    const float* tsb = (const float*)d_in[7];
    const float* qw = (const float*)d_in[8];
    const float* kw = (const float*)d_in[9];
    const float* vw = (const float*)d_in[10];
    const float* wih = (const float*)d_in[11];
    const float* whh = (const float*)d_in[12];
    const float* bih = (const float*)d_in[13];
    const float* bhh = (const float*)d_in[14];
    const float* m1w = (const float*)d_in[15];
    const float* m1b = (const float*)d_in[16];
    const float* m2w = (const float*)d_in[17];
    const float* m2b = (const float*)d_in[18];
    const float* maskw = (const float*)d_in[19];
    const float* maskb = (const float*)d_in[20];
    const float* upw = (const float*)d_in[21];
    const float* upb = (const float*)d_in[22];
    const float* r1w = (const float*)d_in[23];
    const float* r1b = (const float*)d_in[24];
    const float* r2w = (const float*)d_in[25];
    const float* r2b = (const float*)d_in[26];

    float* ws = (float*)d_ws;
    float* slots_g = ws;                         // 524288
    float* rmw  = ws + 524288;                   // 2048
    float* rmb  = ws + 526336;                   // 16 (+pad)
    float* kbf  = ws + 526368;                   // 128
    float* vbf  = ws + 526496;                   // 128
    short* w2bf  = (short*)(ws + 526624);        // 131072 f
    short* wihbf = (short*)(ws + 657696);        // 24576 f
    short* whhbf = (short*)(ws + 682272);        // 24576 f
    short* qwbf  = (short*)(ws + 706848);        // 8192 f
    short* kwf   = (short*)(ws + 715040);        // 8192 f
    short* vwf   = (short*)(ws + 723232);        // 8192 f

    hipLaunchKernelGGL(init_kernel, dim3(512), dim3(256), 0, stream,
                       slot_mu, maskw, maskb, e2w, wih, whh, qw, tsw, tsb, kw, vw,
                       slots_g, rmw, rmb, kbf, vbf,
                       w2bf, wihbf, whhbf, qwbf, kwf, vwf);
    for (int t = 0; t < NSTEP; ++t) {
        hipLaunchKernelGGL(step_kernel, dim3(64), dim3(512), 0, stream,
                           frames, w2bf, e2b, e1w, e1b,
                           kwf, vwf, kbf, vbf, qwbf, wihbf, whhbf, bih, bhh,
                           m1w, m1b, m2w, m2b, upw, upb,
                           r1w, r1b, r2w, r2b, rmw, rmb,
                           slots_g, (float*)d_out, t);
    }
}

// Round 5
// 2203.430 us; speedup vs baseline: 4.0214x; 4.0214x over previous
//
#include <hip/hip_runtime.h>
#include <math.h>

#define B_TOT 512
#define T_FR  18
#define NSTEP 16

typedef __attribute__((ext_vector_type(8))) short bf16x8;
typedef __attribute__((ext_vector_type(4))) float f32x4;

__device__ __forceinline__ float gelu_f(float x) {
    return 0.5f * x * (1.0f + erff(x * 0.70710678118654752f));
}
__device__ __forceinline__ float sigmoid_f(float x) {
    return 1.0f / (1.0f + expf(-x));
}
__device__ __forceinline__ short f2bf(float x) {
    unsigned int u = __float_as_uint(x);
    return (short)((u + 0x7FFFu + ((u >> 16) & 1u)) >> 16);
}
__device__ __forceinline__ float bflo(unsigned int u) { return __uint_as_float(u << 16); }
__device__ __forceinline__ float bfhi(unsigned int u) { return __uint_as_float(u & 0xffff0000u); }
__device__ __forceinline__ float bf2f(short s) {
    return __uint_as_float(((unsigned int)(unsigned short)s) << 16);
}
__device__ __forceinline__ bf16x8 ld_bf8(const short* p) {
    const short4 lo = *reinterpret_cast<const short4*>(p);
    const short4 hi = *reinterpret_cast<const short4*>(p + 4);
    bf16x8 r;
    r[0] = lo.x; r[1] = lo.y; r[2] = lo.z; r[3] = lo.w;
    r[4] = hi.x; r[5] = hi.y; r[6] = hi.z; r[7] = hi.w;
    return r;
}

// ---------------------------------------------------------------- init ----
__global__ __launch_bounds__(256) void init_kernel(
    const float* __restrict__ mask_w, const float* __restrict__ mask_b,
    const float* __restrict__ e2w,
    const float* __restrict__ wih, const float* __restrict__ whh,
    const float* __restrict__ qw,
    const float* __restrict__ tsw, const float* __restrict__ tsb,
    const float* __restrict__ kw, const float* __restrict__ vw,
    float* __restrict__ rmw, float* __restrict__ rmb,
    float* __restrict__ kbf, float* __restrict__ vbf,
    short* __restrict__ w2bf, short* __restrict__ wihbf, short* __restrict__ whhbf,
    short* __restrict__ qwbf, short* __restrict__ kwf, short* __restrict__ vwf)
{
    const int tid = threadIdx.x, bid = blockIdx.x;
    const int gid = bid * 256 + tid, gstr = gridDim.x * 256;
    const float rscale = 0.08838834764831845f;  // 1/sqrt(128)

    for (int i = gid; i < 128 * 2048; i += gstr) w2bf[i] = f2bf(e2w[i]);
    for (int i = gid; i < 384 * 128; i += gstr) {
        wihbf[i] = f2bf(wih[i]);
        whhbf[i] = f2bf(whh[i]);
    }
    for (int i = gid; i < 128 * 128; i += gstr) qwbf[i] = f2bf(qw[i] * rscale);

    if (bid < 128) {
        const int j = bid;
        if (tid < 128) {
            float s = 0.f;
            for (int d = 0; d < 128; ++d) s += kw[j * 128 + d] * tsw[d * 128 + tid];
            kwf[j * 128 + tid] = f2bf(s);
        } else if (tid == 128) {
            float s = 0.f;
            for (int d = 0; d < 128; ++d) s += kw[j * 128 + d] * tsb[d];
            kbf[j] = s;
        }
    } else if (bid < 256) {
        const int j = bid - 128;
        if (tid < 128) {
            float s = 0.f;
            for (int d = 0; d < 128; ++d) s += vw[j * 128 + d] * tsw[d * 128 + tid];
            vwf[j * 128 + tid] = f2bf(s);
        } else if (tid == 128) {
            float s = 0.f;
            for (int d = 0; d < 128; ++d) s += vw[j * 128 + d] * tsb[d];
            vbf[j] = s;
        }
    }
    if (bid == 256) {
        for (int i = tid; i < 2048; i += 256) {
            const int j = i >> 7, d = i & 127;
            float s = 0.f;
            for (int c = 0; c < 128; ++c) s += mask_w[(c * 16 + j) * 128 + d];
            rmw[i] = s * (1.0f / 128.0f);
        }
        for (int i = tid; i < 16; i += 256) {
            float s = 0.f;
            for (int c = 0; c < 128; ++c) s += mask_b[c * 16 + i];
            rmb[i] = s * (1.0f / 128.0f);
        }
    }
}

// ------------------------------------------------- persistent fused kernel ----
// LDS pool offsets (bytes) — persistent region:
#define PO_E1W   0
#define PO_E1B   9216
#define PO_E2B   9728
#define PO_BIH   10240
#define PO_BHH   11776
#define PO_KBF   13312
#define PO_VBF   13824
#define PO_M1B   14336
#define PO_M2W   14464
#define PO_M2B   14720
#define PO_UPB   14736
#define PO_RMB   14768
#define PO_R2B   14832
#define PO_UPW   14848
#define PO_R1W   18944
#define PO_R1B   21248
#define PO_R2W   21504
#define PO_M1W   23808
#define PO_RMW   32000
#define PO_SLOTS 36096
#define PO_SLB   40192
#define SCR      44416
// scratch offsets (relative to SCR):
#define S_PAIR 0
#define S_F1S  2048
#define S_F2T  22528
#define S_KK   0
#define S_VV   4224
#define S_QQ   8448
#define S_UPD  12672
#define S_ATT  16896
#define S_MASK 0
#define S_IMG  8192
#define S_WARP 9216
#define S_DIFF 10240
#define S_M1O  11264
#define S_MOT  12288
#define S_MLL  12352
#define S_R1S  12864
#define POOLSZ (44416 + 29824)

__global__ __launch_bounds__(256, 2) void fused_all_kernel(
    const float* __restrict__ frames,
    const short* __restrict__ w2bf,
    const float* __restrict__ e1w_g, const float* __restrict__ e1b_g,
    const float* __restrict__ e2b_g,
    const float* __restrict__ slot_mu,
    const short* __restrict__ kwf, const short* __restrict__ vwf,
    const float* __restrict__ kbf_g, const float* __restrict__ vbf_g,
    const short* __restrict__ qwbf,
    const short* __restrict__ wihbf, const short* __restrict__ whhbf,
    const float* __restrict__ bih_g, const float* __restrict__ bhh_g,
    const float* __restrict__ m1w_g, const float* __restrict__ m1b_g,
    const float* __restrict__ m2w_g, const float* __restrict__ m2b_g,
    const float* __restrict__ upw_g, const float* __restrict__ upb_g,
    const float* __restrict__ r1w_g, const float* __restrict__ r1b_g,
    const float* __restrict__ r2w_g, const float* __restrict__ r2b_g,
    const float* __restrict__ rmw_g, const float* __restrict__ rmb_g,
    float* __restrict__ out)
{
    __shared__ __align__(16) char POOL[POOLSZ];
    const int tid = threadIdx.x;
    const int lane = tid & 63, w = tid >> 6;          // 4 waves
    const int g = lane >> 4, cn = lane & 15;
    const int b = blockIdx.x;

    float* E1W = (float*)(POOL + PO_E1W);
    float* E1B = (float*)(POOL + PO_E1B);
    float* E2B = (float*)(POOL + PO_E2B);
    float* BIH = (float*)(POOL + PO_BIH);
    float* BHH = (float*)(POOL + PO_BHH);
    float* KBF = (float*)(POOL + PO_KBF);
    float* VBF = (float*)(POOL + PO_VBF);
    float* M1B = (float*)(POOL + PO_M1B);
    float* M2W = (float*)(POOL + PO_M2W);
    float* M2B = (float*)(POOL + PO_M2B);
    float* UPB = (float*)(POOL + PO_UPB);
    float* RMB = (float*)(POOL + PO_RMB);
    float* R2B = (float*)(POOL + PO_R2B);
    float* UPW = (float*)(POOL + PO_UPW);
    float* R1W = (float*)(POOL + PO_R1W);
    float* R1B = (float*)(POOL + PO_R1B);
    float* R2W = (float*)(POOL + PO_R2W);
    short* M1W = (short*)(POOL + PO_M1W);
    short* RMW = (short*)(POOL + PO_RMW);
    float* SLOTS = (float*)(POOL + PO_SLOTS);
    short* SLB = (short*)(POOL + PO_SLB);

    float* PAIR = (float*)(POOL + SCR + S_PAIR);
    short* F1S  = (short*)(POOL + SCR + S_F1S);
    short* F2T  = (short*)(POOL + SCR + S_F2T);
    short* KKl  = (short*)(POOL + SCR + S_KK);
    short* VVl  = (short*)(POOL + SCR + S_VV);
    short* QQB  = (short*)(POOL + SCR + S_QQ);
    short* UPDB = (short*)(POOL + SCR + S_UPD);
    float* ATT  = (float*)(POOL + SCR + S_ATT);
    float* MASKl = (float*)(POOL + SCR + S_MASK);
    float* IMG  = (float*)(POOL + SCR + S_IMG);
    float* WARP = (float*)(POOL + SCR + S_WARP);
    float* DIFF = (float*)(POOL + SCR + S_DIFF);
    float* M1O  = (float*)(POOL + SCR + S_M1O);
    float* MOT  = (float*)(POOL + SCR + S_MOT);
    float* MLL  = (float*)(POOL + SCR + S_MLL);
    short* R1S  = (short*)(POOL + SCR + S_R1S);

    // ---------------- persistent preload ----------------
    for (int i = tid; i < 2304; i += 256) E1W[i] = e1w_g[i];
    if (tid < 128) {
        E1B[tid] = e1b_g[tid]; E2B[tid] = e2b_g[tid];
        KBF[tid] = kbf_g[tid]; VBF[tid] = vbf_g[tid];
    }
    for (int i = tid; i < 384; i += 256) { BIH[i] = bih_g[i]; BHH[i] = bhh_g[i]; }
    if (tid < 32) M1B[tid] = m1b_g[tid];
    if (tid < 64) { M2W[tid] = m2w_g[tid]; R1B[tid] = r1b_g[tid]; }
    if (tid < 2) M2B[tid] = m2b_g[tid];
    if (tid < 8) UPB[tid] = upb_g[tid];
    if (tid < 16) RMB[tid] = rmb_g[tid];
    if (tid == 0) R2B[0] = r2b_g[0];
    for (int i = tid; i < 1024; i += 256) UPW[i] = upw_g[i];
    for (int i = tid; i < 576; i += 256) { R1W[i] = r1w_g[i]; R2W[i] = r2w_g[i]; }
    for (int i = tid; i < 4096; i += 256) M1W[i] = f2bf(m1w_g[i]);
    for (int i = tid; i < 2048; i += 256) RMW[i] = f2bf(rmw_g[i]);
    for (int i = tid; i < 1024; i += 256) {
        const float v = slot_mu[i];
        SLOTS[i] = v;
        SLB[(i >> 7) * 132 + (i & 127)] = f2bf(v);
    }
    for (int i = tid; i < 8 * 132; i += 256) SLB[8 * 132 + i] = 0;

    // ---------------- persistent weight fragments (VGPR) ----------------
    const int col0 = 32 * w;
    bf16x8 bRZ[2][2][8], bNI[2][4], bNH[2][4], bQ[2][4], bKV[4][4];
#pragma unroll
    for (int nt = 0; nt < 2; ++nt) {
        const int col = col0 + nt * 16 + cn;
#pragma unroll
        for (int kt = 0; kt < 4; ++kt) {
            const int ko = kt * 32 + g * 8;
            bQ[nt][kt] = *(const bf16x8*)&qwbf[(size_t)col * 128 + ko];
            bRZ[0][nt][kt]     = *(const bf16x8*)&wihbf[(size_t)col * 128 + ko];
            bRZ[0][nt][kt + 4] = *(const bf16x8*)&whhbf[(size_t)col * 128 + ko];
            bRZ[1][nt][kt]     = *(const bf16x8*)&wihbf[(size_t)(128 + col) * 128 + ko];
            bRZ[1][nt][kt + 4] = *(const bf16x8*)&whhbf[(size_t)(128 + col) * 128 + ko];
            bNI[nt][kt] = *(const bf16x8*)&wihbf[(size_t)(256 + col) * 128 + ko];
            bNH[nt][kt] = *(const bf16x8*)&whhbf[(size_t)(256 + col) * 128 + ko];
        }
    }
    {
        const short* wf = (w >> 1) ? vwf : kwf;
        const int h2 = w & 1;
#pragma unroll
        for (int nt = 0; nt < 4; ++nt)
#pragma unroll
        for (int kt = 0; kt < 4; ++kt)
            bKV[nt][kt] = *(const bf16x8*)
                &wf[(size_t)(h2 * 64 + nt * 16 + cn) * 128 + kt * 32 + g * 8];
    }

    const int py = tid >> 4, pxx = tid & 15;          // pixel for conv phases
    const int arow = (2 * w) * 16 + cn;               // enc2 A row
    const int bcol = (4 * (cn >> 2) + (g & 1) * 2) * 20 + 4 * (cn & 3);
    __syncthreads();

#pragma unroll 1
    for (int t = 0; t < NSTEP; ++t) {
        // ---------------- encoder ----------------
        PAIR[tid]       = frames[((size_t)b * T_FR + t + 1) * 256 + tid];
        PAIR[256 + tid] = frames[((size_t)b * T_FR + t) * 256 + tid];
        __syncthreads();

        float nb0[9], nb1[9];
#pragma unroll
        for (int ky = 0; ky < 3; ++ky)
#pragma unroll
        for (int kx = 0; kx < 3; ++kx) {
            const int yy = py + ky - 1, xx = pxx + kx - 1;
            const bool ok = (yy >= 0 && yy < 16 && xx >= 0 && xx < 16);
            nb0[ky * 3 + kx] = ok ? PAIR[yy * 16 + xx] : 0.f;
            nb1[ky * 3 + kx] = ok ? PAIR[256 + yy * 16 + xx] : 0.f;
        }
        f32x4 acc0 = {0.f, 0.f, 0.f, 0.f};
        f32x4 acc1 = {0.f, 0.f, 0.f, 0.f};
        for (int ch = 0; ch < 4; ++ch) {
            const int ci0 = ch * 32;
#pragma unroll 4
            for (int j = 0; j < 32; ++j) {
                const float* wr = &E1W[(ci0 + j) * 18];
                float a = E1B[ci0 + j];
#pragma unroll
                for (int q = 0; q < 9; ++q) a += nb0[q] * wr[q] + nb1[q] * wr[q + 9];
                F1S[j * 320 + py * 20 + pxx] = f2bf(gelu_f(a));
            }
            __syncthreads();
            int rb = (g >> 1) * 320 + bcol;
            int k0 = ch * 512 + g * 8;
            for (int kt = 0; kt < 16; ++kt) {
                const short4 lo = *(const short4*)&F1S[rb];
                const short4 hi = *(const short4*)&F1S[rb + 20];
                bf16x8 bfr;
                bfr[0] = lo.x; bfr[1] = lo.y; bfr[2] = lo.z; bfr[3] = lo.w;
                bfr[4] = hi.x; bfr[5] = hi.y; bfr[6] = hi.z; bfr[7] = hi.w;
                const bf16x8 a0 = *(const bf16x8*)&w2bf[(size_t)arow * 2048 + k0];
                const bf16x8 a1 = *(const bf16x8*)&w2bf[(size_t)(arow + 16) * 2048 + k0];
                acc0 = __builtin_amdgcn_mfma_f32_16x16x32_bf16(a0, bfr, acc0, 0, 0, 0);
                acc1 = __builtin_amdgcn_mfma_f32_16x16x32_bf16(a1, bfr, acc1, 0, 0, 0);
                rb += 640; k0 += 32;
            }
            __syncthreads();
        }
        {
            const int cob0 = (2 * w) * 16 + g * 4;
            short4 s0, s1;
            s0.x = f2bf(gelu_f(acc0[0] + E2B[cob0]));
            s0.y = f2bf(gelu_f(acc0[1] + E2B[cob0 + 1]));
            s0.z = f2bf(gelu_f(acc0[2] + E2B[cob0 + 2]));
            s0.w = f2bf(gelu_f(acc0[3] + E2B[cob0 + 3]));
            s1.x = f2bf(gelu_f(acc1[0] + E2B[cob0 + 16]));
            s1.y = f2bf(gelu_f(acc1[1] + E2B[cob0 + 17]));
            s1.z = f2bf(gelu_f(acc1[2] + E2B[cob0 + 18]));
            s1.w = f2bf(gelu_f(acc1[3] + E2B[cob0 + 19]));
            *(short4*)&F2T[cn * 132 + cob0] = s0;
            *(short4*)&F2T[cn * 132 + cob0 + 16] = s1;
        }
        __syncthreads();

        // ---------------- kk/vv (MFMA, fused weights) ----------------
        {
            bf16x8 aT[4];
#pragma unroll
            for (int kt = 0; kt < 4; ++kt)
                aT[kt] = ld_bf8(&F2T[cn * 132 + kt * 32 + g * 8]);
            f32x4 ac[4];
#pragma unroll
            for (int nt = 0; nt < 4; ++nt) ac[nt] = (f32x4){0.f, 0.f, 0.f, 0.f};
#pragma unroll
            for (int kt = 0; kt < 4; ++kt)
#pragma unroll
            for (int nt = 0; nt < 4; ++nt)
                ac[nt] = __builtin_amdgcn_mfma_f32_16x16x32_bf16(aT[kt], bKV[nt][kt], ac[nt], 0, 0, 0);
            short* dst = (w >> 1) ? VVl : KKl;
            const float* bias = (w >> 1) ? VBF : KBF;
            const int h2 = w & 1;
#pragma unroll
            for (int nt = 0; nt < 4; ++nt) {
                const int j = h2 * 64 + nt * 16 + cn;
                const float bb = bias[j];
#pragma unroll
                for (int r = 0; r < 4; ++r)
                    dst[(4 * g + r) * 132 + j] = f2bf(ac[nt][r] + bb);
            }
        }
        __syncthreads();

        // ---------------- slot attention: 3 iterations ----------------
        for (int it = 0; it < 3; ++it) {
            bf16x8 aS[4];
#pragma unroll
            for (int kt = 0; kt < 4; ++kt)
                aS[kt] = ld_bf8(&SLB[cn * 132 + kt * 32 + g * 8]);
            {
                f32x4 qa[2] = {{0.f, 0.f, 0.f, 0.f}, {0.f, 0.f, 0.f, 0.f}};
#pragma unroll
                for (int kt = 0; kt < 4; ++kt)
#pragma unroll
                for (int nt = 0; nt < 2; ++nt)
                    qa[nt] = __builtin_amdgcn_mfma_f32_16x16x32_bf16(aS[kt], bQ[nt][kt], qa[nt], 0, 0, 0);
#pragma unroll
                for (int nt = 0; nt < 2; ++nt)
#pragma unroll
                for (int r = 0; r < 4; ++r)
                    QQB[(4 * g + r) * 132 + col0 + nt * 16 + cn] = f2bf(qa[nt][r]);
            }
            __syncthreads();
            if (tid < 128) {
                const int kq = tid >> 4, n = tid & 15;
                float a = 0.f;
                for (int d = 0; d < 128; d += 4) {
                    const uint2 q2 = *(const uint2*)&QQB[kq * 132 + d];
                    const uint2 k2 = *(const uint2*)&KKl[n * 132 + d];
                    a += bflo(q2.x) * bflo(k2.x) + bfhi(q2.x) * bfhi(k2.x)
                       + bflo(q2.y) * bflo(k2.y) + bfhi(q2.y) * bfhi(k2.y);
                }
                ATT[kq * 16 + n] = a;
            }
            __syncthreads();
            if (tid < 16) {
                const int n = tid;
                float m = -1e30f;
#pragma unroll
                for (int kq = 0; kq < 8; ++kq) m = fmaxf(m, ATT[kq * 16 + n]);
                float e[8], ssum = 0.f;
#pragma unroll
                for (int kq = 0; kq < 8; ++kq) { e[kq] = expf(ATT[kq * 16 + n] - m); ssum += e[kq]; }
                const float inv = 1.f / ssum;
#pragma unroll
                for (int kq = 0; kq < 8; ++kq) ATT[kq * 16 + n] = e[kq] * inv;
            }
            __syncthreads();
            {
                const int k8 = tid >> 5, lg = tid & 31;
                float a0 = 0.f, a1 = 0.f, a2 = 0.f, a3 = 0.f;
#pragma unroll
                for (int n = 0; n < 16; ++n) {
                    const float at = ATT[k8 * 16 + n];
                    const uint2 v2 = *(const uint2*)&VVl[n * 132 + 4 * lg];
                    a0 += at * bflo(v2.x); a1 += at * bfhi(v2.x);
                    a2 += at * bflo(v2.y); a3 += at * bfhi(v2.y);
                }
                short4 sv;
                sv.x = f2bf(a0); sv.y = f2bf(a1); sv.z = f2bf(a2); sv.w = f2bf(a3);
                *(short4*)&UPDB[k8 * 132 + 4 * lg] = sv;
                short4 zz4; zz4.x = 0; zz4.y = 0; zz4.z = 0; zz4.w = 0;
                *(short4*)&UPDB[(8 + k8) * 132 + 4 * lg] = zz4;
            }
            __syncthreads();
            {
                bf16x8 aU[4];
#pragma unroll
                for (int kt = 0; kt < 4; ++kt)
                    aU[kt] = ld_bf8(&UPDB[cn * 132 + kt * 32 + g * 8]);
                f32x4 aR[2], aZ[2], aNIv[2], aNHv[2];
#pragma unroll
                for (int nt = 0; nt < 2; ++nt) {
                    aR[nt] = (f32x4){0.f, 0.f, 0.f, 0.f};
                    aZ[nt] = (f32x4){0.f, 0.f, 0.f, 0.f};
                    aNIv[nt] = (f32x4){0.f, 0.f, 0.f, 0.f};
                    aNHv[nt] = (f32x4){0.f, 0.f, 0.f, 0.f};
                }
#pragma unroll
                for (int nt = 0; nt < 2; ++nt)
#pragma unroll
                for (int kt = 0; kt < 4; ++kt) {
                    aR[nt] = __builtin_amdgcn_mfma_f32_16x16x32_bf16(aU[kt], bRZ[0][nt][kt], aR[nt], 0, 0, 0);
                    aR[nt] = __builtin_amdgcn_mfma_f32_16x16x32_bf16(aS[kt], bRZ[0][nt][kt + 4], aR[nt], 0, 0, 0);
                    aZ[nt] = __builtin_amdgcn_mfma_f32_16x16x32_bf16(aU[kt], bRZ[1][nt][kt], aZ[nt], 0, 0, 0);
                    aZ[nt] = __builtin_amdgcn_mfma_f32_16x16x32_bf16(aS[kt], bRZ[1][nt][kt + 4], aZ[nt], 0, 0, 0);
                    aNIv[nt] = __builtin_amdgcn_mfma_f32_16x16x32_bf16(aU[kt], bNI[nt][kt], aNIv[nt], 0, 0, 0);
                    aNHv[nt] = __builtin_amdgcn_mfma_f32_16x16x32_bf16(aS[kt], bNH[nt][kt], aNHv[nt], 0, 0, 0);
                }
                __syncthreads();   // A-frag reads done before SLB rewrite
                if (g < 2) {
#pragma unroll
                    for (int nt = 0; nt < 2; ++nt) {
                        const int colj = col0 + nt * 16 + cn;
                        const float br = BIH[colj] + BHH[colj];
                        const float bz = BIH[128 + colj] + BHH[128 + colj];
                        const float bi = BIH[256 + colj], bh = BHH[256 + colj];
#pragma unroll
                        for (int r = 0; r < 4; ++r) {
                            const int kq = 4 * g + r;
                            const float rr = sigmoid_f(aR[nt][r] + br);
                            const float zz = sigmoid_f(aZ[nt][r] + bz);
                            const float nn = tanhf(aNIv[nt][r] + bi + rr * (aNHv[nt][r] + bh));
                            const float hold = SLOTS[kq * 128 + colj];
                            const float hv = (1.f - zz) * nn + zz * hold;
                            SLOTS[kq * 128 + colj] = hv;
                            SLB[kq * 132 + colj] = f2bf(hv);
                        }
                    }
                }
                __syncthreads();
            }
        }

        // ---------------- decode ----------------
        IMG[tid] = frames[((size_t)b * T_FR + t + 1) * 256 + tid];
        {
            const int kq = tid >> 5, c = tid & 31;
            float a = M1B[c];
            for (int d = 0; d < 128; d += 4) {
                const uint2 s2 = *(const uint2*)&SLB[kq * 132 + d];
                const uint2 w2 = *(const uint2*)&M1W[c * 128 + d];
                a += bflo(s2.x) * bflo(w2.x) + bfhi(s2.x) * bfhi(w2.x)
                   + bflo(s2.y) * bflo(w2.y) + bfhi(s2.y) * bfhi(w2.y);
            }
            M1O[kq * 32 + c] = gelu_f(a);
        }
        if (tid < 128) {
            const int kq = tid >> 4, j = tid & 15;
            float a = RMB[j];
            for (int d = 0; d < 128; d += 4) {
                const uint2 s2 = *(const uint2*)&SLB[kq * 132 + d];
                const uint2 w2 = *(const uint2*)&RMW[j * 128 + d];
                a += bflo(s2.x) * bflo(w2.x) + bfhi(s2.x) * bfhi(w2.x)
                   + bflo(s2.y) * bflo(w2.y) + bfhi(s2.y) * bfhi(w2.y);
            }
            MLL[kq * 16 + j] = a;
        }
        __syncthreads();
        if (tid < 16) {
            const int kq = tid >> 1, e = tid & 1;
            float a = M2B[e];
#pragma unroll
            for (int c = 0; c < 32; ++c) a += M1O[kq * 32 + c] * M2W[e * 32 + c];
            MOT[kq * 2 + e] = tanhf(a) * 4.0f;
        }
        {
            const int jj = (py >> 2) * 4 + (pxx >> 2);
            const int wq = (py & 3) * 4 + (pxx & 3);
#pragma unroll
            for (int ko = 0; ko < 8; ++ko) {
                float a = UPB[ko];
#pragma unroll
                for (int i8 = 0; i8 < 8; ++i8)
                    a += MLL[i8 * 16 + jj] * UPW[(i8 * 8 + ko) * 16 + wq];
                MASKl[ko * 256 + tid] = a;
            }
        }
        __syncthreads();
        {
            float m = -1e30f;
#pragma unroll
            for (int kq = 0; kq < 8; ++kq) m = fmaxf(m, MASKl[kq * 256 + tid]);
            float e[8], ssum = 0.f;
#pragma unroll
            for (int kq = 0; kq < 8; ++kq) { e[kq] = expf(MASKl[kq * 256 + tid] - m); ssum += e[kq]; }
            const float inv = 1.f / ssum;
            const float gxv = -1.0f + (2.0f / 15.0f) * pxx;
            const float gyv = -1.0f + (2.0f / 15.0f) * py;
            float wsum = 0.f;
#pragma unroll
            for (int kq = 0; kq < 8; ++kq) {
                const float fx = MOT[kq * 2 + 0] * 0.125f;
                const float fy = MOT[kq * 2 + 1] * 0.125f;
                const float sgx = fminf(fmaxf(gxv + fx, -1.f), 1.f);
                const float sgy = fminf(fmaxf(gyv + fy, -1.f), 1.f);
                const float ix = (sgx + 1.f) * 7.5f;
                const float iy = (sgy + 1.f) * 7.5f;
                const float x0f = floorf(ix), y0f = floorf(iy);
                const float wx = ix - x0f, wy = iy - y0f;
                const int x0 = (int)x0f, y0 = (int)y0f;
                const int x1 = min(x0 + 1, 15), y1 = min(y0 + 1, 15);
                const float v00 = IMG[y0 * 16 + x0], v01 = IMG[y0 * 16 + x1];
                const float v10 = IMG[y1 * 16 + x0], v11 = IMG[y1 * 16 + x1];
                const float val = (1.f - wy) * ((1.f - wx) * v00 + wx * v01) +
                                  wy * ((1.f - wx) * v10 + wx * v11);
                wsum += (e[kq] * inv) * val;
            }
            WARP[tid] = wsum;
            DIFF[tid] = wsum - IMG[tid];
        }
        __syncthreads();
        float nbz[9];
#pragma unroll
        for (int ky = 0; ky < 3; ++ky)
#pragma unroll
        for (int kx = 0; kx < 3; ++kx) {
            const int y2 = py + ky - 1, x2 = pxx + kx - 1;
            const bool ok = (y2 >= 0 && y2 < 16 && x2 >= 0 && x2 < 16);
            nbz[ky * 3 + kx] = ok ? DIFF[y2 * 16 + x2] : 0.f;
        }
        float racc = 0.f;
        for (int c0 = 0; c0 < 64; c0 += 32) {
#pragma unroll 4
            for (int cl = 0; cl < 32; ++cl) {
                const int c = c0 + cl;
                float a = R1B[c];
#pragma unroll
                for (int q = 0; q < 9; ++q) a += nbz[q] * R1W[c * 9 + q];
                R1S[cl * 264 + tid] = f2bf(gelu_f(a));
            }
            __syncthreads();
#pragma unroll 4
            for (int cl = 0; cl < 32; ++cl) {
                const float* r2r = &R2W[(c0 + cl) * 9];
#pragma unroll
                for (int ky = 0; ky < 3; ++ky)
#pragma unroll
                for (int kx = 0; kx < 3; ++kx) {
                    const int y2 = py + ky - 1, x2 = pxx + kx - 1;
                    if (y2 >= 0 && y2 < 16 && x2 >= 0 && x2 < 16)
                        racc += bf2f(R1S[cl * 264 + y2 * 16 + x2]) * r2r[ky * 3 + kx];
                }
            }
            __syncthreads();
        }
        const float resv = tanhf(racc + R2B[0]) * 0.1f;
        const float pred = fminf(fmaxf(WARP[tid] + resv, 0.f), 1.f);
        out[((size_t)b * NSTEP + t) * 256 + tid] = pred;
        __syncthreads();   // scratch safe for next step
    }
}

// -------------------------------------------------------------- launch ----
extern "C" void kernel_launch(void* const* d_in, const int* in_sizes, int n_in,
                              void* d_out, int out_size, void* d_ws, size_t ws_size,
                              hipStream_t stream)
{
    const float* frames = (const float*)d_in[0];
    const float* e1w = (const float*)d_in[1];
    const float* e1b = (const float*)d_in[2];
    const float* e2w = (const float*)d_in[3];
    const float* e2b = (const float*)d_in[4];
    const float* slot_mu = (const float*)d_in[5];
    const float* tsw = (const float*)d_in[6];
    const float* tsb = (const float*)d_in[7];
    const float* qw = (const float*)d_in[8];
    const float* kw = (const float*)d_in[9];
    const float* vw = (const float*)d_in[10];
    const float* wih = (const float*)d_in[11];
    const float* whh = (const float*)d_in[12];
    const float* bih = (const float*)d_in[13];
    const float* bhh = (const float*)d_in[14];
    const float* m1w = (const float*)d_in[15];
    const float* m1b = (const float*)d_in[16];
    const float* m2w = (const float*)d_in[17];
    const float* m2b = (const float*)d_in[18];
    const float* maskw = (const float*)d_in[19];
    const float* maskb = (const float*)d_in[20];
    const float* upw = (const float*)d_in[21];
    const float* upb = (const float*)d_in[22];
    const float* r1w = (const float*)d_in[23];
    const float* r1b = (const float*)d_in[24];
    const float* r2w = (const float*)d_in[25];
    const float* r2b = (const float*)d_in[26];

    float* ws = (float*)d_ws;
    float* rmw  = ws + 0;                        // 2048
    float* rmb  = ws + 2048;                     // 16 (pad to 2064)
    float* kbf  = ws + 2064;                     // 128
    float* vbf  = ws + 2192;                     // 128 -> 2320
    short* w2bf  = (short*)(ws + 2320);          // 131072 f
    short* wihbf = (short*)(ws + 133392);        // 24576 f
    short* whhbf = (short*)(ws + 157968);        // 24576 f
    short* qwbf  = (short*)(ws + 182544);        // 8192 f
    short* kwf   = (short*)(ws + 190736);        // 8192 f
    short* vwf   = (short*)(ws + 198928);        // 8192 f

    hipLaunchKernelGGL(init_kernel, dim3(512), dim3(256), 0, stream,
                       maskw, maskb, e2w, wih, whh, qw, tsw, tsb, kw, vw,
                       rmw, rmb, kbf, vbf, w2bf, wihbf, whhbf, qwbf, kwf, vwf);
    hipLaunchKernelGGL(fused_all_kernel, dim3(512), dim3(256), 0, stream,
                       frames, w2bf, e1w, e1b, e2b, slot_mu,
                       kwf, vwf, kbf, vbf, qwbf, wihbf, whhbf, bih, bhh,
                       m1w, m1b, m2w, m2b, upw, upb,
                       r1w, r1b, r2w, r2b, rmw, rmb,
                       (float*)d_out);
}